// Round 24
// baseline (128.541 us; speedup 1.0000x reference)
//
#include <hip/hip_runtime.h>

// VQ codebook via MFMA: z_e (262144,64) f32, embeddings (512,64) f32.
// Outputs (flat f32): z_q_st [N*D], indices-as-float [N], loss [1].
//
// R24: SPLIT-RESIDENCE codebook. Hi bf16 fragments (64KB) persistent in LDS;
// lo fragments streamed per tile from global (coalesced 16B/lane, L2/L1-hot,
// one voffset + imm-2048 covers both). LDS ~70KB -> 2 blocks/CU x 1024 thr
// = 8 waves/SIMD (R21-R23 lesson: 4 waves/SIMD cannot hide the ~350cyc/tile
// serial path; no pipe exceeded 36%). Grid 512 x 512 tokens, single pass,
// 32 tokens/wave. Per-chain MFMA accumulation order / argmin / rescan /
// epilogue bitwise = R21/R23 (absmax 0 x12) -- only the e0l/e1l operand
// SOURCE changes (same values from the same prep kernel).
// Spill canary: WRITE_SIZE must stay ~67MB (VGPR est ~60 < 64 cap).

typedef short  bf16x8 __attribute__((ext_vector_type(8)));
typedef float  f32x4  __attribute__((ext_vector_type(4)));

static constexpr int N_TOK = 262144;
static constexpr int K     = 512;
static constexpr int D     = 64;
static constexpr float THRESH = 0.01f;
static constexpr int NBLK_A = N_TOK / 512;    // 512 blocks (2 per CU)

// ws layout (bytes)
static constexpr size_t WS_ESQ   = 0;         //  512 f32 (2048 B)
static constexpr size_t WS_BL    = 2048;      //  512 f32 (2048 B)
static constexpr size_t WS_EFRAG = 10240;     // 65536 u16 (131072 B), 16B-al

#define GLDS16(G, L) __builtin_amdgcn_global_load_lds(                    \
    (const __attribute__((address_space(1))) void*)(G),                   \
    (__attribute__((address_space(3))) void*)(L), 16, 0, 0)

// ---- prep: E' = -2E -> bf16 hi/lo A-frags, fused with esq ------------------
__global__ __launch_bounds__(512) void prep_kernel(
    const float* __restrict__ emb, unsigned short* __restrict__ ef,
    float* __restrict__ esq) {
  int idx  = blockIdx.x * 512 + threadIdx.x;   // 32768 = 512 codes * 64 d
  int code = idx >> 6, d = idx & 63;
  float s  = -2.0f * emb[code * 64 + d];
  unsigned u  = __float_as_uint(s);
  unsigned hi = (u + 0x7FFFu + ((u >> 16) & 1u)) >> 16;       // RNE bf16
  float lof   = s - __uint_as_float(hi << 16);
  unsigned v2 = __float_as_uint(lof);
  unsigned lo = (v2 + 0x7FFFu + ((v2 >> 16) & 1u)) >> 16;     // RNE bf16
  int tile = code >> 4, row = code & 15;
  int c = (d >> 5) & 1, g = (d >> 3) & 3, i = d & 7;
  int lane = row + (g << 4);
  size_t base = ((size_t)tile * 256 + (size_t)c * 128) * 8;
  ef[base + (size_t)(0 * 64 + lane) * 8 + i] = (unsigned short)hi;
  ef[base + (size_t)(1 * 64 + lane) * 8 + i] = (unsigned short)lo;
  // esq for this block's 8 codes (rows L1-hot from the reads above).
  if (threadIdx.x < 8) {
    int k = blockIdx.x * 8 + threadIdx.x;
    const float4* row4 = reinterpret_cast<const float4*>(emb + (size_t)k * D);
    float acc = 0.f;
#pragma unroll
    for (int j = 0; j < 16; ++j) {
      float4 v = row4[j];
      acc = fmaf(v.x, v.x, acc); acc = fmaf(v.y, v.y, acc);
      acc = fmaf(v.z, v.z, acc); acc = fmaf(v.w, v.w, acc);
    }
    esq[k] = acc;
  }
}

// RNE bf16 two-term split of 8 floats -> hi/lo bf16x8.
__device__ __forceinline__ void split8(float4 a, float4 b,
                                       bf16x8& h, bf16x8& lo) {
  float v[8] = {a.x, a.y, a.z, a.w, b.x, b.y, b.z, b.w};
#pragma unroll
  for (int i = 0; i < 8; ++i) {
    unsigned u  = __float_as_uint(v[i]);
    unsigned hi = (u + 0x7FFFu + ((u >> 16) & 1u)) >> 16;
    float lof   = v[i] - __uint_as_float(hi << 16);
    unsigned v2 = __float_as_uint(lof);
    unsigned l2 = (v2 + 0x7FFFu + ((v2 >> 16) & 1u)) >> 16;
    h[i]  = (short)hi;
    lo[i] = (short)l2;
  }
}

#define ARGMIN4(C, BASE, BEST, SECOND, BIDXV)               \
  {                                                         \
    _Pragma("unroll")                                       \
    for (int r = 0; r < 4; ++r) {                           \
      float v = (C)[r];                                     \
      bool lt = v < (BEST);                                 \
      float mn = fminf((SECOND), v);                        \
      (SECOND) = lt ? (BEST) : mn;                          \
      (BIDXV)  = lt ? ((BASE) + r) : (BIDXV);               \
      (BEST)   = lt ? v : (BEST);                           \
    }                                                       \
  }

// ---- kernel A: split-residence MFMA + rescan + fused epilogue --------------
__global__ __launch_bounds__(1024) void vq_mfma(
    const float* __restrict__ z_e, const float* __restrict__ emb,
    const unsigned short* __restrict__ efrag, const float* __restrict__ esq_g,
    float* __restrict__ out_zq, float* __restrict__ out_idx,
    float* __restrict__ block_loss) {
  __shared__ float esql[K];                         // 2 KB
  __shared__ __align__(16) short lds_eh[32768];     // 64 KB: hi frags only
  __shared__ int   sIdx[512];                       // 2 KB (per-wave slices)
  __shared__ float wsm[16];

  const int t  = threadIdx.x;                       // 0..1023
  const int l  = t & 63;
  const int wu = __builtin_amdgcn_readfirstlane(t >> 6);  // wave 0..15
  const int g  = l >> 4, g4 = g << 2;
  const int tok0 = blockIdx.x * 512 + wu * 32;      // wave's 32 tokens

  if (t < K) esql[t] = esq_g[t];

  const bf16x8* EF = reinterpret_cast<const bf16x8*>(efrag);
  // Stage HI frags only: 4 rounds; wave (r*16+wu) covers (tile, c) hi row.
#pragma unroll
  for (int r = 0; r < 4; ++r) {
    const int fh = r * 16 + wu;                     // wave-uniform
    const int tile = fh >> 1, c = fh & 1;
    GLDS16(EF + (size_t)tile * 256 + c * 128 + l,   // hi block (part 0)
           &lds_eh[r * 8192 + wu * 512]);
  }

  // z frags for rows tok0+(l&15) [A] and +16 [B]. RNE split = efrag's.
  bf16x8 zh0A, zl0A, zh1A, zl1A, zh0B, zl0B, zh1B, zl1B;
  {
    const int rowA = tok0 + (l & 15);
    const float* zp = z_e + (size_t)rowA * D + g * 8;
    float4 q0 = *reinterpret_cast<const float4*>(zp);
    float4 q1 = *reinterpret_cast<const float4*>(zp + 4);
    float4 q2 = *reinterpret_cast<const float4*>(zp + 32);
    float4 q3 = *reinterpret_cast<const float4*>(zp + 36);
    split8(q0, q1, zh0A, zl0A);
    split8(q2, q3, zh1A, zl1A);
    zp += (size_t)16 * D;                           // rowB = rowA + 16
    q0 = *reinterpret_cast<const float4*>(zp);
    q1 = *reinterpret_cast<const float4*>(zp + 4);
    q2 = *reinterpret_cast<const float4*>(zp + 32);
    q3 = *reinterpret_cast<const float4*>(zp + 36);
    split8(q0, q1, zh0B, zl0B);
    split8(q2, q3, zh1B, zl1B);
  }

  asm volatile("s_waitcnt vmcnt(0)" ::: "memory");
  __builtin_amdgcn_s_barrier();                     // one-time; none after

  float bestA = 3.402823466e38f, secondA = 3.402823466e38f;
  float bestB = 3.402823466e38f, secondB = 3.402823466e38f;
  int idxA = 0, idxB = 0;

  for (int tile = 0; tile < 32; ++tile) {           // ascending code order
    // lo frags from global (coalesced; L1/L2-hot), hi frags from LDS.
    const bf16x8* loP = EF + (size_t)tile * 256 + 64 + l;
    bf16x8 e0l = loP[0];                            // part1, c=0
    bf16x8 e1l = loP[128];                          // part1, c=1 (+2048B)
    const bf16x8* tbh =
        reinterpret_cast<const bf16x8*>(&lds_eh[(size_t)tile * 1024]);
    bf16x8 e0h = tbh[l], e1h = tbh[64 + l];

    f32x4 CA = *reinterpret_cast<const f32x4*>(&esql[tile * 16 + g4]);
    f32x4 CB = CA;
    __builtin_amdgcn_s_setprio(1);
    CA = __builtin_amdgcn_mfma_f32_16x16x32_bf16(e0h, zh0A, CA, 0, 0, 0);
    CB = __builtin_amdgcn_mfma_f32_16x16x32_bf16(e0h, zh0B, CB, 0, 0, 0);
    CA = __builtin_amdgcn_mfma_f32_16x16x32_bf16(e0h, zl0A, CA, 0, 0, 0);
    CB = __builtin_amdgcn_mfma_f32_16x16x32_bf16(e0h, zl0B, CB, 0, 0, 0);
    CA = __builtin_amdgcn_mfma_f32_16x16x32_bf16(e0l, zh0A, CA, 0, 0, 0);
    CB = __builtin_amdgcn_mfma_f32_16x16x32_bf16(e0l, zh0B, CB, 0, 0, 0);
    CA = __builtin_amdgcn_mfma_f32_16x16x32_bf16(e1h, zh1A, CA, 0, 0, 0);
    CB = __builtin_amdgcn_mfma_f32_16x16x32_bf16(e1h, zh1B, CB, 0, 0, 0);
    CA = __builtin_amdgcn_mfma_f32_16x16x32_bf16(e1h, zl1A, CA, 0, 0, 0);
    CB = __builtin_amdgcn_mfma_f32_16x16x32_bf16(e1h, zl1B, CB, 0, 0, 0);
    CA = __builtin_amdgcn_mfma_f32_16x16x32_bf16(e1l, zh1A, CA, 0, 0, 0);
    CB = __builtin_amdgcn_mfma_f32_16x16x32_bf16(e1l, zh1B, CB, 0, 0, 0);
    __builtin_amdgcn_s_setprio(0);

    const int base = tile * 16 + g4;
    ARGMIN4(CA, base, bestA, secondA, idxA)
    ARGMIN4(CB, base, bestB, secondB, idxB)
  }

  // Reduce across lanes {l, l^16, l^32, l^48}; ties -> smaller code.
#pragma unroll
  for (int mask = 16; mask <= 32; mask <<= 1) {
    float ob, os; int oi; bool take; float hi2;
    ob = __shfl_xor(bestA, mask); oi = __shfl_xor(idxA, mask);
    os = __shfl_xor(secondA, mask);
    hi2 = fmaxf(bestA, ob);
    secondA = fminf(secondA, fminf(os, hi2));
    take = (ob < bestA) || (ob == bestA && oi < idxA);
    bestA = take ? ob : bestA; idxA = take ? oi : idxA;

    ob = __shfl_xor(bestB, mask); oi = __shfl_xor(idxB, mask);
    os = __shfl_xor(secondB, mask);
    hi2 = fmaxf(bestB, ob);
    secondB = fminf(secondB, fminf(os, hi2));
    take = (ob < bestB) || (ob == bestB && oi < idxB);
    bestB = take ? ob : bestB; idxB = take ? oi : idxB;
  }

  if (l < 16) {
    sIdx[wu * 32 + l]      = idxA;
    sIdx[wu * 32 + 16 + l] = idxB;
  }

  // Inline exact rescan of flagged tokens (same-wave ballot loop).
  {
    bool fA = (l < 16) && ((secondA - bestA) < THRESH);
    bool fB = (l < 16) && ((secondB - bestB) < THRESH);
    unsigned long long ba = __ballot(fA);
    unsigned long long bb = __ballot(fB);
    unsigned mask = (unsigned)((ba & 0xFFFFull) | ((bb & 0xFFFFull) << 16));
    while (mask) {
      const int j = __builtin_ctz(mask);
      mask &= mask - 1;
      const int n = tok0 + j;
      const float4* zr = reinterpret_cast<const float4*>(z_e + (size_t)n * D);
      float best = 3.402823466e38f; int bid = 0;
#pragma unroll 1
      for (int half2 = 0; half2 < 2; ++half2) {
        float acc[4];
#pragma unroll
        for (int m = 0; m < 4; ++m) acc[m] = 0.f;
#pragma unroll 1
        for (int i = 0; i < 16; ++i) {
          float4 z4 = zr[i];                       // uniform addr broadcast
#pragma unroll
          for (int m = 0; m < 4; ++m) {
            const float4 e4 = *reinterpret_cast<const float4*>(
                emb + (size_t)(l + 64 * (half2 * 4 + m)) * D + 4 * i);
            acc[m] = fmaf(z4.x, e4.x, acc[m]);
            acc[m] = fmaf(z4.y, e4.y, acc[m]);
            acc[m] = fmaf(z4.z, e4.z, acc[m]);
            acc[m] = fmaf(z4.w, e4.w, acc[m]);
          }
        }
#pragma unroll
        for (int m = 0; m < 4; ++m) {
          const int code = l + 64 * (half2 * 4 + m);
          float s = fmaf(-2.f, acc[m], esq_g[code]);
          if (s < best) { best = s; bid = code; }  // ascending overall
        }
      }
#pragma unroll
      for (int mk = 1; mk <= 32; mk <<= 1) {       // lexicographic min
        float ob = __shfl_xor(best, mk);
        int   oi = __shfl_xor(bid, mk);
        bool take = (ob < best) || (ob == best && oi < bid);
        best = take ? ob : best;
        bid  = take ? oi : bid;
      }
      if (l == 0) sIdx[wu * 32 + j] = bid;         // same-wave patch
    }
  }
  // No barrier: sIdx[wu*32..+32) produced and consumed by wave wu only.

  // Fused epilogue: 2 lanes/token within the wave.
  {
    const int tk = l >> 1, h = l & 1;
    const int n = tok0 + tk;
    const int bi = sIdx[wu * 32 + tk];
    const float4* er = reinterpret_cast<const float4*>(emb + (size_t)bi * D);
    const float4* zr = reinterpret_cast<const float4*>(z_e + (size_t)n * D);
    float4* orow = reinterpret_cast<float4*>(out_zq + (size_t)n * D);
    float lsum = 0.f;
#pragma unroll
    for (int j = 0; j < 8; ++j) {
      int i = h * 8 + j;
      float4 Q = er[i], Z = zr[i];
      float dx = Q.x - Z.x, dy = Q.y - Z.y, dz = Q.z - Z.z, dw = Q.w - Z.w;
      float4 st;
      st.x = Z.x + dx; st.y = Z.y + dy; st.z = Z.z + dz; st.w = Z.w + dw;
      orow[i] = st;
      lsum = fmaf(dx, dx, lsum); lsum = fmaf(dy, dy, lsum);
      lsum = fmaf(dz, dz, lsum); lsum = fmaf(dw, dw, lsum);
    }
    if (h == 0) out_idx[n] = (float)bi;
    float s = lsum;
#pragma unroll
    for (int off = 32; off > 0; off >>= 1) s += __shfl_xor(s, off, 64);
    if (l == 0) wsm[wu] = s;
  }
  __syncthreads();
  if (t == 0) {
    float s = 0.f;
#pragma unroll
    for (int i = 0; i < 16; ++i) s += wsm[i];      // fixed ascending order
    block_loss[blockIdx.x] = s;
  }
}

// ---- finalize loss (deterministic tree, 512 partials) ----------------------
__global__ __launch_bounds__(256) void loss_finalize(
    const float* __restrict__ bl, float* __restrict__ out_loss) {
  __shared__ float sm[256];
  const int t = threadIdx.x;
  sm[t] = bl[t] + bl[t + 256];
  __syncthreads();
#pragma unroll
  for (int off = 128; off > 0; off >>= 1) {
    if (t < off) sm[t] += sm[t + off];
    __syncthreads();
  }
  if (t == 0) out_loss[0] = sm[0] * (1.0f / 16777216.0f);  // /(N*D)
}

extern "C" void kernel_launch(void* const* d_in, const int* in_sizes, int n_in,
                              void* d_out, int out_size, void* d_ws, size_t ws_size,
                              hipStream_t stream) {
  const float* z_e = (const float*)d_in[0];
  const float* emb = (const float*)d_in[1];

  float* out      = (float*)d_out;
  float* out_zq   = out;                          // N*D
  float* out_idx  = out + (size_t)N_TOK * D;      // N
  float* out_loss = out_idx + N_TOK;              // 1

  char* wsb = (char*)d_ws;
  float*          esqp = (float*)(wsb + WS_ESQ);
  float*          bl   = (float*)(wsb + WS_BL);
  unsigned short* ef   = (unsigned short*)(wsb + WS_EFRAG);

  prep_kernel<<<64, 512, 0, stream>>>(emb, ef, esqp);
  vq_mfma<<<NBLK_A, 1024, 0, stream>>>(z_e, emb, ef, esqp, out_zq, out_idx, bl);
  loss_finalize<<<1, 256, 0, stream>>>(bl, out_loss);
}

// Round 25
// 105.609 us; speedup vs baseline: 1.2171x; 1.2171x over previous
//
#include <hip/hip_runtime.h>

// VQ codebook via MFMA: z_e (262144,64) f32, embeddings (512,64) f32.
// Outputs (flat f32): z_q_st [N*D], indices-as-float [N], loss [1].
//
// R25 = R21 (persistent 128KB codebook, 1 block/CU, 16 waves, zero-barrier
// loop, 2 token-groups) with SPLIT ACCUMULATORS: per group, Ch = esq +
// e0h*zh0 + e1h*zh1 (chain depth 2) and Cl = e0h*zl0 + e0l*zh0 + e1h*zl1 +
// e1l*zh1 (depth 4), merged by 4 VALU adds before ARGMIN. Same 12 MFMA/tile
// but 4 independent chains (2,4,2,4) instead of 2 chains of depth 6 -> MFMA
// critical path -33% and no cross-tile C carry. Reordered summation shifts
// distances <=1 ulp of partials -- absorbed by THRESH=0.01 guard (err bound
// ~2.5e-3) -> selections exact via rescan. R24 lesson: occupancy axis closed
// (2nd block never co-resident; global-lo streams regressed). Rolled loop
// (R23 unroll neutral). Spill canary: WRITE_SIZE must stay ~66.7MB.

typedef short  bf16x8 __attribute__((ext_vector_type(8)));
typedef float  f32x4  __attribute__((ext_vector_type(4)));

static constexpr int N_TOK = 262144;
static constexpr int K     = 512;
static constexpr int D     = 64;
static constexpr float THRESH = 0.01f;
static constexpr int NBLK_A = N_TOK / 1024;   // 256 blocks (1 per CU)

// ws layout (bytes)
static constexpr size_t WS_ESQ   = 0;         //  512 f32 (2048 B)
static constexpr size_t WS_BL    = 2048;      //  256 f32 (1024 B)
static constexpr size_t WS_EFRAG = 10240;     // 65536 u16 (131072 B), 16B-al

#define GLDS16(G, L) __builtin_amdgcn_global_load_lds(                    \
    (const __attribute__((address_space(1))) void*)(G),                   \
    (__attribute__((address_space(3))) void*)(L), 16, 0, 0)

// ---- prep: E' = -2E -> bf16 hi/lo A-frags, fused with esq ------------------
__global__ __launch_bounds__(512) void prep_kernel(
    const float* __restrict__ emb, unsigned short* __restrict__ ef,
    float* __restrict__ esq) {
  int idx  = blockIdx.x * 512 + threadIdx.x;   // 32768 = 512 codes * 64 d
  int code = idx >> 6, d = idx & 63;
  float s  = -2.0f * emb[code * 64 + d];
  unsigned u  = __float_as_uint(s);
  unsigned hi = (u + 0x7FFFu + ((u >> 16) & 1u)) >> 16;       // RNE bf16
  float lof   = s - __uint_as_float(hi << 16);
  unsigned v2 = __float_as_uint(lof);
  unsigned lo = (v2 + 0x7FFFu + ((v2 >> 16) & 1u)) >> 16;     // RNE bf16
  int tile = code >> 4, row = code & 15;
  int c = (d >> 5) & 1, g = (d >> 3) & 3, i = d & 7;
  int lane = row + (g << 4);
  size_t base = ((size_t)tile * 256 + (size_t)c * 128) * 8;
  ef[base + (size_t)(0 * 64 + lane) * 8 + i] = (unsigned short)hi;
  ef[base + (size_t)(1 * 64 + lane) * 8 + i] = (unsigned short)lo;
  // esq for this block's 8 codes (rows L1-hot from the reads above).
  if (threadIdx.x < 8) {
    int k = blockIdx.x * 8 + threadIdx.x;
    const float4* row4 = reinterpret_cast<const float4*>(emb + (size_t)k * D);
    float acc = 0.f;
#pragma unroll
    for (int j = 0; j < 16; ++j) {
      float4 v = row4[j];
      acc = fmaf(v.x, v.x, acc); acc = fmaf(v.y, v.y, acc);
      acc = fmaf(v.z, v.z, acc); acc = fmaf(v.w, v.w, acc);
    }
    esq[k] = acc;
  }
}

// RNE bf16 two-term split of 8 floats -> hi/lo bf16x8.
__device__ __forceinline__ void split8(float4 a, float4 b,
                                       bf16x8& h, bf16x8& lo) {
  float v[8] = {a.x, a.y, a.z, a.w, b.x, b.y, b.z, b.w};
#pragma unroll
  for (int i = 0; i < 8; ++i) {
    unsigned u  = __float_as_uint(v[i]);
    unsigned hi = (u + 0x7FFFu + ((u >> 16) & 1u)) >> 16;
    float lof   = v[i] - __uint_as_float(hi << 16);
    unsigned v2 = __float_as_uint(lof);
    unsigned l2 = (v2 + 0x7FFFu + ((v2 >> 16) & 1u)) >> 16;
    h[i]  = (short)hi;
    lo[i] = (short)l2;
  }
}

#define ARGMIN4(C, BASE, BEST, SECOND, BIDXV)               \
  {                                                         \
    _Pragma("unroll")                                       \
    for (int r = 0; r < 4; ++r) {                           \
      float v = (C)[r];                                     \
      bool lt = v < (BEST);                                 \
      float mn = fminf((SECOND), v);                        \
      (SECOND) = lt ? (BEST) : mn;                          \
      (BIDXV)  = lt ? ((BASE) + r) : (BIDXV);               \
      (BEST)   = lt ? v : (BEST);                           \
    }                                                       \
  }

// ---- kernel A: persistent-codebook MFMA + rescan + fused epilogue ----------
__global__ __launch_bounds__(1024) void vq_mfma(
    const float* __restrict__ z_e, const float* __restrict__ emb,
    const unsigned short* __restrict__ efrag, const float* __restrict__ esq_g,
    float* __restrict__ out_zq, float* __restrict__ out_idx,
    float* __restrict__ block_loss) {
  __shared__ float esql[K];                         // 2 KB
  __shared__ __align__(16) short lds_e[65536];      // 128 KB: all 32 tiles
  __shared__ int   sIdx[512];                       // 2 KB (per-wave slices)
  __shared__ float wsm[16];

  const int t  = threadIdx.x;                       // 0..1023
  const int l  = t & 63;
  const int wu = __builtin_amdgcn_readfirstlane(t >> 6);  // wave 0..15
  const int g  = l >> 4, g4 = g << 2;
  const int blk0 = blockIdx.x * 1024;               // this block's tokens

  if (t < K) esql[t] = esq_g[t];

  const bf16x8* EF = reinterpret_cast<const bf16x8*>(efrag);
  // Stage the whole codebook frag array: 8 rounds x 16KB (1024 thr x 16B).
#pragma unroll
  for (int r = 0; r < 8; ++r)
    GLDS16(EF + r * 1024 + t, &lds_e[r * 8192 + wu * 512]);
  asm volatile("s_waitcnt vmcnt(0)" ::: "memory");
  __builtin_amdgcn_s_barrier();                     // one-time; none after

  float blsum = 0.f;

  for (int pass = 0; pass < 2; ++pass) {
    const int tok0 = blk0 + pass * 512 + wu * 32;   // wave's 32 tokens

    // z frags for rows tok0+(l&15) [A] and +16 [B]. RNE split = efrag's.
    bf16x8 zh0A, zl0A, zh1A, zl1A, zh0B, zl0B, zh1B, zl1B;
    {
      const int rowA = tok0 + (l & 15);
      const float* zp = z_e + (size_t)rowA * D + g * 8;
      float4 q0 = *reinterpret_cast<const float4*>(zp);
      float4 q1 = *reinterpret_cast<const float4*>(zp + 4);
      float4 q2 = *reinterpret_cast<const float4*>(zp + 32);
      float4 q3 = *reinterpret_cast<const float4*>(zp + 36);
      split8(q0, q1, zh0A, zl0A);
      split8(q2, q3, zh1A, zl1A);
      zp += (size_t)16 * D;                         // rowB = rowA + 16
      q0 = *reinterpret_cast<const float4*>(zp);
      q1 = *reinterpret_cast<const float4*>(zp + 4);
      q2 = *reinterpret_cast<const float4*>(zp + 32);
      q3 = *reinterpret_cast<const float4*>(zp + 36);
      split8(q0, q1, zh0B, zl0B);
      split8(q2, q3, zh1B, zl1B);
    }

    float bestA = 3.402823466e38f, secondA = 3.402823466e38f;
    float bestB = 3.402823466e38f, secondB = 3.402823466e38f;
    int idxA = 0, idxB = 0;

    for (int tile = 0; tile < 32; ++tile) {         // ascending code order
      const bf16x8* tb =
          reinterpret_cast<const bf16x8*>(&lds_e[(size_t)tile * 2048]);
      bf16x8 e0h = tb[l], e0l = tb[64 + l];
      bf16x8 e1h = tb[128 + l], e1l = tb[192 + l];

      // Split accumulators: Ch (depth-2 chain) + Cl (depth-4 chain).
      f32x4 ChA = *reinterpret_cast<const f32x4*>(&esql[tile * 16 + g4]);
      f32x4 ChB = ChA;
      f32x4 ClA = {0.f, 0.f, 0.f, 0.f};
      f32x4 ClB = {0.f, 0.f, 0.f, 0.f};
      __builtin_amdgcn_s_setprio(1);
      ChA = __builtin_amdgcn_mfma_f32_16x16x32_bf16(e0h, zh0A, ChA, 0, 0, 0);
      ChB = __builtin_amdgcn_mfma_f32_16x16x32_bf16(e0h, zh0B, ChB, 0, 0, 0);
      ClA = __builtin_amdgcn_mfma_f32_16x16x32_bf16(e0h, zl0A, ClA, 0, 0, 0);
      ClB = __builtin_amdgcn_mfma_f32_16x16x32_bf16(e0h, zl0B, ClB, 0, 0, 0);
      ChA = __builtin_amdgcn_mfma_f32_16x16x32_bf16(e1h, zh1A, ChA, 0, 0, 0);
      ChB = __builtin_amdgcn_mfma_f32_16x16x32_bf16(e1h, zh1B, ChB, 0, 0, 0);
      ClA = __builtin_amdgcn_mfma_f32_16x16x32_bf16(e0l, zh0A, ClA, 0, 0, 0);
      ClB = __builtin_amdgcn_mfma_f32_16x16x32_bf16(e0l, zh0B, ClB, 0, 0, 0);
      ClA = __builtin_amdgcn_mfma_f32_16x16x32_bf16(e1h, zl1A, ClA, 0, 0, 0);
      ClB = __builtin_amdgcn_mfma_f32_16x16x32_bf16(e1h, zl1B, ClB, 0, 0, 0);
      ClA = __builtin_amdgcn_mfma_f32_16x16x32_bf16(e1l, zh1A, ClA, 0, 0, 0);
      ClB = __builtin_amdgcn_mfma_f32_16x16x32_bf16(e1l, zh1B, ClB, 0, 0, 0);
      __builtin_amdgcn_s_setprio(0);

      // Merge (4 VALU adds per group) -> breaks cross-tile C carry.
      f32x4 CA, CB;
#pragma unroll
      for (int r = 0; r < 4; ++r) { CA[r] = ChA[r] + ClA[r]; }
#pragma unroll
      for (int r = 0; r < 4; ++r) { CB[r] = ChB[r] + ClB[r]; }

      const int base = tile * 16 + g4;
      ARGMIN4(CA, base, bestA, secondA, idxA)
      ARGMIN4(CB, base, bestB, secondB, idxB)
    }

    // Reduce across lanes {l, l^16, l^32, l^48}; ties -> smaller code.
#pragma unroll
    for (int mask = 16; mask <= 32; mask <<= 1) {
      float ob, os; int oi; bool take; float hi2;
      ob = __shfl_xor(bestA, mask); oi = __shfl_xor(idxA, mask);
      os = __shfl_xor(secondA, mask);
      hi2 = fmaxf(bestA, ob);
      secondA = fminf(secondA, fminf(os, hi2));
      take = (ob < bestA) || (ob == bestA && oi < idxA);
      bestA = take ? ob : bestA; idxA = take ? oi : idxA;

      ob = __shfl_xor(bestB, mask); oi = __shfl_xor(idxB, mask);
      os = __shfl_xor(secondB, mask);
      hi2 = fmaxf(bestB, ob);
      secondB = fminf(secondB, fminf(os, hi2));
      take = (ob < bestB) || (ob == bestB && oi < idxB);
      bestB = take ? ob : bestB; idxB = take ? oi : idxB;
    }

    if (l < 16) {
      sIdx[wu * 32 + l]      = idxA;
      sIdx[wu * 32 + 16 + l] = idxB;
    }

    // Inline exact rescan of flagged tokens (same-wave ballot loop).
    {
      bool fA = (l < 16) && ((secondA - bestA) < THRESH);
      bool fB = (l < 16) && ((secondB - bestB) < THRESH);
      unsigned long long ba = __ballot(fA);
      unsigned long long bb = __ballot(fB);
      unsigned mask = (unsigned)((ba & 0xFFFFull) | ((bb & 0xFFFFull) << 16));
      while (mask) {
        const int j = __builtin_ctz(mask);
        mask &= mask - 1;
        const int n = tok0 + j;
        const float4* zr =
            reinterpret_cast<const float4*>(z_e + (size_t)n * D);
        float best = 3.402823466e38f; int bid = 0;
#pragma unroll 1
        for (int half2 = 0; half2 < 2; ++half2) {
          float acc[4];
#pragma unroll
          for (int m = 0; m < 4; ++m) acc[m] = 0.f;
#pragma unroll 1
          for (int i = 0; i < 16; ++i) {
            float4 z4 = zr[i];                     // uniform addr broadcast
#pragma unroll
            for (int m = 0; m < 4; ++m) {
              const float4 e4 = *reinterpret_cast<const float4*>(
                  emb + (size_t)(l + 64 * (half2 * 4 + m)) * D + 4 * i);
              acc[m] = fmaf(z4.x, e4.x, acc[m]);
              acc[m] = fmaf(z4.y, e4.y, acc[m]);
              acc[m] = fmaf(z4.z, e4.z, acc[m]);
              acc[m] = fmaf(z4.w, e4.w, acc[m]);
            }
          }
#pragma unroll
          for (int m = 0; m < 4; ++m) {
            const int code = l + 64 * (half2 * 4 + m);
            float s = fmaf(-2.f, acc[m], esq_g[code]);
            if (s < best) { best = s; bid = code; }
          }
        }
#pragma unroll
        for (int mk = 1; mk <= 32; mk <<= 1) {     // lexicographic min
          float ob = __shfl_xor(best, mk);
          int   oi = __shfl_xor(bid, mk);
          bool take = (ob < best) || (ob == best && oi < bid);
          best = take ? ob : best;
          bid  = take ? oi : bid;
        }
        if (l == 0) sIdx[wu * 32 + j] = bid;       // same-wave patch
      }
    }
    // No barrier: sIdx[wu*32..+32) produced and consumed by wave wu only.

    // Fused epilogue: 2 lanes/token within the wave.
    {
      const int tk = l >> 1, h = l & 1;
      const int n = tok0 + tk;
      const int bi = sIdx[wu * 32 + tk];
      const float4* er =
          reinterpret_cast<const float4*>(emb + (size_t)bi * D);
      const float4* zr =
          reinterpret_cast<const float4*>(z_e + (size_t)n * D);
      float4* orow = reinterpret_cast<float4*>(out_zq + (size_t)n * D);
      float lsum = 0.f;
#pragma unroll
      for (int j = 0; j < 8; ++j) {
        int i = h * 8 + j;
        float4 Q = er[i], Z = zr[i];
        float dx = Q.x - Z.x, dy = Q.y - Z.y, dz = Q.z - Z.z, dw = Q.w - Z.w;
        float4 st;
        st.x = Z.x + dx; st.y = Z.y + dy; st.z = Z.z + dz; st.w = Z.w + dw;
        orow[i] = st;
        lsum = fmaf(dx, dx, lsum); lsum = fmaf(dy, dy, lsum);
        lsum = fmaf(dz, dz, lsum); lsum = fmaf(dw, dw, lsum);
      }
      if (h == 0) out_idx[n] = (float)bi;
      float s = lsum;
#pragma unroll
      for (int off = 32; off > 0; off >>= 1) s += __shfl_xor(s, off, 64);
      blsum += s;                                  // uniform across lanes
    }
  }

  if (l == 0) wsm[wu] = blsum;
  __syncthreads();
  if (t == 0) {
    float s = 0.f;
#pragma unroll
    for (int i = 0; i < 16; ++i) s += wsm[i];      // fixed ascending order
    block_loss[blockIdx.x] = s;
  }
}

// ---- finalize loss (deterministic tree, 256 partials) ----------------------
__global__ __launch_bounds__(256) void loss_finalize(
    const float* __restrict__ bl, float* __restrict__ out_loss) {
  __shared__ float sm[256];
  const int t = threadIdx.x;
  sm[t] = bl[t];
  __syncthreads();
#pragma unroll
  for (int off = 128; off > 0; off >>= 1) {
    if (t < off) sm[t] += sm[t + off];
    __syncthreads();
  }
  if (t == 0) out_loss[0] = sm[0] * (1.0f / 16777216.0f);  // /(N*D)
}

extern "C" void kernel_launch(void* const* d_in, const int* in_sizes, int n_in,
                              void* d_out, int out_size, void* d_ws, size_t ws_size,
                              hipStream_t stream) {
  const float* z_e = (const float*)d_in[0];
  const float* emb = (const float*)d_in[1];

  float* out      = (float*)d_out;
  float* out_zq   = out;                          // N*D
  float* out_idx  = out + (size_t)N_TOK * D;      // N
  float* out_loss = out_idx + N_TOK;              // 1

  char* wsb = (char*)d_ws;
  float*          esqp = (float*)(wsb + WS_ESQ);
  float*          bl   = (float*)(wsb + WS_BL);
  unsigned short* ef   = (unsigned short*)(wsb + WS_EFRAG);

  prep_kernel<<<64, 512, 0, stream>>>(emb, ef, esqp);
  vq_mfma<<<NBLK_A, 1024, 0, stream>>>(z_e, emb, ef, esqp, out_zq, out_idx, bl);
  loss_finalize<<<1, 256, 0, stream>>>(bl, out_loss);
}

// Round 26
// 102.456 us; speedup vs baseline: 1.2546x; 1.0308x over previous
//
#include <hip/hip_runtime.h>

// VQ codebook via MFMA: z_e (262144,64) f32, embeddings (512,64) f32.
// Outputs (flat f32): z_q_st [N*D], indices-as-float [N], loss [1].
//
// R26 = R23 (best, 103.7us) minus s_setprio. Last untested hot-loop variable:
// setprio carried since R14 without A/B; T5's prerequisite (wave role-split)
// is absent in this barrier-free uniform loop (all 16 waves identical), and
// m190 measured setprio NEGATIVE in exactly this regime. 64 toggles/wave of
// pure SALU + scheduler thrash, zero arbitration benefit expected.
// Everything else byte-identical to R23 (absmax 0 x14 rounds).

typedef short  bf16x8 __attribute__((ext_vector_type(8)));
typedef float  f32x4  __attribute__((ext_vector_type(4)));

static constexpr int N_TOK = 262144;
static constexpr int K     = 512;
static constexpr int D     = 64;
static constexpr float THRESH = 0.01f;
static constexpr int NBLK_A = N_TOK / 1024;   // 256 blocks (1 per CU)

// ws layout (bytes)
static constexpr size_t WS_ESQ   = 0;         //  512 f32 (2048 B)
static constexpr size_t WS_BL    = 2048;      //  256 f32 (1024 B)
static constexpr size_t WS_EFRAG = 10240;     // 65536 u16 (131072 B), 16B-al

#define GLDS16(G, L) __builtin_amdgcn_global_load_lds(                    \
    (const __attribute__((address_space(1))) void*)(G),                   \
    (__attribute__((address_space(3))) void*)(L), 16, 0, 0)

// ---- prep: E' = -2E -> bf16 hi/lo A-frags, fused with esq ------------------
__global__ __launch_bounds__(512) void prep_kernel(
    const float* __restrict__ emb, unsigned short* __restrict__ ef,
    float* __restrict__ esq) {
  int idx  = blockIdx.x * 512 + threadIdx.x;   // 32768 = 512 codes * 64 d
  int code = idx >> 6, d = idx & 63;
  float s  = -2.0f * emb[code * 64 + d];
  unsigned u  = __float_as_uint(s);
  unsigned hi = (u + 0x7FFFu + ((u >> 16) & 1u)) >> 16;       // RNE bf16
  float lof   = s - __uint_as_float(hi << 16);
  unsigned v2 = __float_as_uint(lof);
  unsigned lo = (v2 + 0x7FFFu + ((v2 >> 16) & 1u)) >> 16;     // RNE bf16
  int tile = code >> 4, row = code & 15;
  int c = (d >> 5) & 1, g = (d >> 3) & 3, i = d & 7;
  int lane = row + (g << 4);
  size_t base = ((size_t)tile * 256 + (size_t)c * 128) * 8;
  ef[base + (size_t)(0 * 64 + lane) * 8 + i] = (unsigned short)hi;
  ef[base + (size_t)(1 * 64 + lane) * 8 + i] = (unsigned short)lo;
  // esq for this block's 8 codes (rows L1-hot from the reads above).
  if (threadIdx.x < 8) {
    int k = blockIdx.x * 8 + threadIdx.x;
    const float4* row4 = reinterpret_cast<const float4*>(emb + (size_t)k * D);
    float acc = 0.f;
#pragma unroll
    for (int j = 0; j < 16; ++j) {
      float4 v = row4[j];
      acc = fmaf(v.x, v.x, acc); acc = fmaf(v.y, v.y, acc);
      acc = fmaf(v.z, v.z, acc); acc = fmaf(v.w, v.w, acc);
    }
    esq[k] = acc;
  }
}

// RNE bf16 two-term split of 8 floats -> hi/lo bf16x8.
__device__ __forceinline__ void split8(float4 a, float4 b,
                                       bf16x8& h, bf16x8& lo) {
  float v[8] = {a.x, a.y, a.z, a.w, b.x, b.y, b.z, b.w};
#pragma unroll
  for (int i = 0; i < 8; ++i) {
    unsigned u  = __float_as_uint(v[i]);
    unsigned hi = (u + 0x7FFFu + ((u >> 16) & 1u)) >> 16;
    float lof   = v[i] - __uint_as_float(hi << 16);
    unsigned v2 = __float_as_uint(lof);
    unsigned l2 = (v2 + 0x7FFFu + ((v2 >> 16) & 1u)) >> 16;
    h[i]  = (short)hi;
    lo[i] = (short)l2;
  }
}

#define ARGMIN4(C, BASE, BEST, SECOND, BIDXV)               \
  {                                                         \
    _Pragma("unroll")                                       \
    for (int r = 0; r < 4; ++r) {                           \
      float v = (C)[r];                                     \
      bool lt = v < (BEST);                                 \
      float mn = fminf((SECOND), v);                        \
      (SECOND) = lt ? (BEST) : mn;                          \
      (BIDXV)  = lt ? ((BASE) + r) : (BIDXV);               \
      (BEST)   = lt ? v : (BEST);                           \
    }                                                       \
  }

// ---- kernel A: persistent-codebook MFMA + rescan + fused epilogue ----------
__global__ __launch_bounds__(1024) void vq_mfma(
    const float* __restrict__ z_e, const float* __restrict__ emb,
    const unsigned short* __restrict__ efrag, const float* __restrict__ esq_g,
    float* __restrict__ out_zq, float* __restrict__ out_idx,
    float* __restrict__ block_loss) {
  __shared__ float esql[K];                         // 2 KB
  __shared__ __align__(16) short lds_e[65536];      // 128 KB: all 32 tiles
  __shared__ int   sIdx[512];                       // 2 KB (per-wave slices)
  __shared__ float wsm[16];

  const int t  = threadIdx.x;                       // 0..1023
  const int l  = t & 63;
  const int wu = __builtin_amdgcn_readfirstlane(t >> 6);  // wave 0..15
  const int g  = l >> 4, g4 = g << 2;
  const int blk0 = blockIdx.x * 1024;               // this block's tokens

  if (t < K) esql[t] = esq_g[t];

  const bf16x8* EF = reinterpret_cast<const bf16x8*>(efrag);
  // Stage the whole codebook frag array: 8 rounds x 16KB (1024 thr x 16B).
#pragma unroll
  for (int r = 0; r < 8; ++r)
    GLDS16(EF + r * 1024 + t, &lds_e[r * 8192 + wu * 512]);
  asm volatile("s_waitcnt vmcnt(0)" ::: "memory");
  __builtin_amdgcn_s_barrier();                     // one-time; none after

  float blsum = 0.f;

  for (int pass = 0; pass < 2; ++pass) {
    const int tok0 = blk0 + pass * 512 + wu * 32;   // wave's 32 tokens

    // z frags for rows tok0+(l&15) [A] and +16 [B]. RNE split = efrag's.
    bf16x8 zh0A, zl0A, zh1A, zl1A, zh0B, zl0B, zh1B, zl1B;
    {
      const int rowA = tok0 + (l & 15);
      const float* zp = z_e + (size_t)rowA * D + g * 8;
      float4 q0 = *reinterpret_cast<const float4*>(zp);
      float4 q1 = *reinterpret_cast<const float4*>(zp + 4);
      float4 q2 = *reinterpret_cast<const float4*>(zp + 32);
      float4 q3 = *reinterpret_cast<const float4*>(zp + 36);
      split8(q0, q1, zh0A, zl0A);
      split8(q2, q3, zh1A, zl1A);
      zp += (size_t)16 * D;                         // rowB = rowA + 16
      q0 = *reinterpret_cast<const float4*>(zp);
      q1 = *reinterpret_cast<const float4*>(zp + 4);
      q2 = *reinterpret_cast<const float4*>(zp + 32);
      q3 = *reinterpret_cast<const float4*>(zp + 36);
      split8(q0, q1, zh0B, zl0B);
      split8(q2, q3, zh1B, zl1B);
    }

    float bestA = 3.402823466e38f, secondA = 3.402823466e38f;
    float bestB = 3.402823466e38f, secondB = 3.402823466e38f;
    int idxA = 0, idxB = 0;

#pragma unroll 2
    for (int tile = 0; tile < 32; ++tile) {         // ascending code order
      const bf16x8* tb =
          reinterpret_cast<const bf16x8*>(&lds_e[(size_t)tile * 2048]);
      f32x4 CA = *reinterpret_cast<const f32x4*>(&esql[tile * 16 + g4]);
      f32x4 CB = CA;
      bf16x8 e0h = tb[l], e0l = tb[64 + l];
      bf16x8 e1h = tb[128 + l], e1l = tb[192 + l];
      CA = __builtin_amdgcn_mfma_f32_16x16x32_bf16(e0h, zh0A, CA, 0, 0, 0);
      CB = __builtin_amdgcn_mfma_f32_16x16x32_bf16(e0h, zh0B, CB, 0, 0, 0);
      CA = __builtin_amdgcn_mfma_f32_16x16x32_bf16(e0h, zl0A, CA, 0, 0, 0);
      CB = __builtin_amdgcn_mfma_f32_16x16x32_bf16(e0h, zl0B, CB, 0, 0, 0);
      CA = __builtin_amdgcn_mfma_f32_16x16x32_bf16(e0l, zh0A, CA, 0, 0, 0);
      CB = __builtin_amdgcn_mfma_f32_16x16x32_bf16(e0l, zh0B, CB, 0, 0, 0);
      CA = __builtin_amdgcn_mfma_f32_16x16x32_bf16(e1h, zh1A, CA, 0, 0, 0);
      CB = __builtin_amdgcn_mfma_f32_16x16x32_bf16(e1h, zh1B, CB, 0, 0, 0);
      CA = __builtin_amdgcn_mfma_f32_16x16x32_bf16(e1h, zl1A, CA, 0, 0, 0);
      CB = __builtin_amdgcn_mfma_f32_16x16x32_bf16(e1h, zl1B, CB, 0, 0, 0);
      CA = __builtin_amdgcn_mfma_f32_16x16x32_bf16(e1l, zh1A, CA, 0, 0, 0);
      CB = __builtin_amdgcn_mfma_f32_16x16x32_bf16(e1l, zh1B, CB, 0, 0, 0);

      const int base = tile * 16 + g4;
      ARGMIN4(CA, base, bestA, secondA, idxA)
      ARGMIN4(CB, base, bestB, secondB, idxB)
    }

    // Reduce across lanes {l, l^16, l^32, l^48}; ties -> smaller code.
#pragma unroll
    for (int mask = 16; mask <= 32; mask <<= 1) {
      float ob, os; int oi; bool take; float hi2;
      ob = __shfl_xor(bestA, mask); oi = __shfl_xor(idxA, mask);
      os = __shfl_xor(secondA, mask);
      hi2 = fmaxf(bestA, ob);
      secondA = fminf(secondA, fminf(os, hi2));
      take = (ob < bestA) || (ob == bestA && oi < idxA);
      bestA = take ? ob : bestA; idxA = take ? oi : idxA;

      ob = __shfl_xor(bestB, mask); oi = __shfl_xor(idxB, mask);
      os = __shfl_xor(secondB, mask);
      hi2 = fmaxf(bestB, ob);
      secondB = fminf(secondB, fminf(os, hi2));
      take = (ob < bestB) || (ob == bestB && oi < idxB);
      bestB = take ? ob : bestB; idxB = take ? oi : idxB;
    }

    if (l < 16) {
      sIdx[wu * 32 + l]      = idxA;
      sIdx[wu * 32 + 16 + l] = idxB;
    }

    // Inline exact rescan of flagged tokens (same-wave ballot loop).
    {
      bool fA = (l < 16) && ((secondA - bestA) < THRESH);
      bool fB = (l < 16) && ((secondB - bestB) < THRESH);
      unsigned long long ba = __ballot(fA);
      unsigned long long bb = __ballot(fB);
      unsigned mask = (unsigned)((ba & 0xFFFFull) | ((bb & 0xFFFFull) << 16));
      while (mask) {
        const int j = __builtin_ctz(mask);
        mask &= mask - 1;
        const int n = tok0 + j;
        const float4* zr =
            reinterpret_cast<const float4*>(z_e + (size_t)n * D);
        float best = 3.402823466e38f; int bid = 0;
#pragma unroll 1
        for (int half2 = 0; half2 < 2; ++half2) {
          float acc[4];
#pragma unroll
          for (int m = 0; m < 4; ++m) acc[m] = 0.f;
#pragma unroll 1
          for (int i = 0; i < 16; ++i) {
            float4 z4 = zr[i];                     // uniform addr broadcast
#pragma unroll
            for (int m = 0; m < 4; ++m) {
              const float4 e4 = *reinterpret_cast<const float4*>(
                  emb + (size_t)(l + 64 * (half2 * 4 + m)) * D + 4 * i);
              acc[m] = fmaf(z4.x, e4.x, acc[m]);
              acc[m] = fmaf(z4.y, e4.y, acc[m]);
              acc[m] = fmaf(z4.z, e4.z, acc[m]);
              acc[m] = fmaf(z4.w, e4.w, acc[m]);
            }
          }
#pragma unroll
          for (int m = 0; m < 4; ++m) {
            const int code = l + 64 * (half2 * 4 + m);
            float s = fmaf(-2.f, acc[m], esq_g[code]);
            if (s < best) { best = s; bid = code; }
          }
        }
#pragma unroll
        for (int mk = 1; mk <= 32; mk <<= 1) {     // lexicographic min
          float ob = __shfl_xor(best, mk);
          int   oi = __shfl_xor(bid, mk);
          bool take = (ob < best) || (ob == best && oi < bid);
          best = take ? ob : best;
          bid  = take ? oi : bid;
        }
        if (l == 0) sIdx[wu * 32 + j] = bid;       // same-wave patch
      }
    }
    // No barrier: sIdx[wu*32..+32) produced and consumed by wave wu only.

    // Fused epilogue: 2 lanes/token within the wave.
    {
      const int tk = l >> 1, h = l & 1;
      const int n = tok0 + tk;
      const int bi = sIdx[wu * 32 + tk];
      const float4* er =
          reinterpret_cast<const float4*>(emb + (size_t)bi * D);
      const float4* zr =
          reinterpret_cast<const float4*>(z_e + (size_t)n * D);
      float4* orow = reinterpret_cast<float4*>(out_zq + (size_t)n * D);
      float lsum = 0.f;
#pragma unroll
      for (int j = 0; j < 8; ++j) {
        int i = h * 8 + j;
        float4 Q = er[i], Z = zr[i];
        float dx = Q.x - Z.x, dy = Q.y - Z.y, dz = Q.z - Z.z, dw = Q.w - Z.w;
        float4 st;
        st.x = Z.x + dx; st.y = Z.y + dy; st.z = Z.z + dz; st.w = Z.w + dw;
        orow[i] = st;
        lsum = fmaf(dx, dx, lsum); lsum = fmaf(dy, dy, lsum);
        lsum = fmaf(dz, dz, lsum); lsum = fmaf(dw, dw, lsum);
      }
      if (h == 0) out_idx[n] = (float)bi;
      float s = lsum;
#pragma unroll
      for (int off = 32; off > 0; off >>= 1) s += __shfl_xor(s, off, 64);
      blsum += s;                                  // uniform across lanes
    }
  }

  if (l == 0) wsm[wu] = blsum;
  __syncthreads();
  if (t == 0) {
    float s = 0.f;
#pragma unroll
    for (int i = 0; i < 16; ++i) s += wsm[i];      // fixed ascending order
    block_loss[blockIdx.x] = s;
  }
}

// ---- finalize loss (deterministic tree, 256 partials) ----------------------
__global__ __launch_bounds__(256) void loss_finalize(
    const float* __restrict__ bl, float* __restrict__ out_loss) {
  __shared__ float sm[256];
  const int t = threadIdx.x;
  sm[t] = bl[t];
  __syncthreads();
#pragma unroll
  for (int off = 128; off > 0; off >>= 1) {
    if (t < off) sm[t] += sm[t + off];
    __syncthreads();
  }
  if (t == 0) out_loss[0] = sm[0] * (1.0f / 16777216.0f);  // /(N*D)
}

extern "C" void kernel_launch(void* const* d_in, const int* in_sizes, int n_in,
                              void* d_out, int out_size, void* d_ws, size_t ws_size,
                              hipStream_t stream) {
  const float* z_e = (const float*)d_in[0];
  const float* emb = (const float*)d_in[1];

  float* out      = (float*)d_out;
  float* out_zq   = out;                          // N*D
  float* out_idx  = out + (size_t)N_TOK * D;      // N
  float* out_loss = out_idx + N_TOK;              // 1

  char* wsb = (char*)d_ws;
  float*          esqp = (float*)(wsb + WS_ESQ);
  float*          bl   = (float*)(wsb + WS_BL);
  unsigned short* ef   = (unsigned short*)(wsb + WS_EFRAG);

  prep_kernel<<<64, 512, 0, stream>>>(emb, ef, esqp);
  vq_mfma<<<NBLK_A, 1024, 0, stream>>>(z_e, emb, ef, esqp, out_zq, out_idx, bl);
  loss_finalize<<<1, 256, 0, stream>>>(bl, out_loss);
}